// Round 5
// baseline (14386.136 us; speedup 1.0000x reference)
//
#include <hip/hip_runtime.h>
#include <math.h>

// FNO2d: B=8, CIN=2, COUT=1, W0=64, modes 16x16, NL=4, H=W=256
// h stored channels-last: [B][H][W][64]
// Y (F1 out): [B][H(x)][16ky][64c][2]   (shares buffer with A)
// Xf (F2 out): [B][64c][256m][2], m = kx*16+ky
// A (I1 out): [B][H(x)][16ky][64o][2]

#define NLAYER 4

// ws offsets in floats
#define OFF_H    0L
#define SZ_H     33554432L            // 8*256*256*64
#define OFF_YA   33554432L
#define SZ_YA    4194304L             // 8*256*16*64*2
#define OFF_XF   37748736L
#define SZ_XF    262144L              // 8*64*256*2
#define OFF_TAB  38010880L
#define OFF_PWT  38011136L            // 4*64*64
#define OFF_O1T  38027520L            // 64*32
#define WS_FLOATS 38029568L

__global__ void k_init(float* __restrict__ ws, const float* __restrict__ pw_w,
                       const float* __restrict__ o1_w) {
  float* costab = ws + OFF_TAB;
  float* pwT = ws + OFF_PWT;
  float* o1T = ws + OFF_O1T;
  int t = blockIdx.x * blockDim.x + threadIdx.x;
  int stride = gridDim.x * blockDim.x;
  for (int m = t; m < 256; m += stride)
    costab[m] = (float)cos((double)m * (3.14159265358979323846 / 128.0));
  for (int idx = t; idx < NLAYER * 64 * 64; idx += stride) {
    int l = idx >> 12; int r = idx & 4095; int i = r >> 6; int o = r & 63;
    pwT[idx] = pw_w[((l * 64 + o) << 6) + i];   // pwT[l][i][o] = pw_w[l][o][i]
  }
  for (int idx = t; idx < 64 * 32; idx += stride) {
    int i = idx >> 5; int o = idx & 31;
    o1T[idx] = o1_w[(o << 6) + i];              // o1T[i][o] = o1_w[o][i]
  }
}

// input 1x1 conv: x [B][2][H][W] -> h [B][H][W][64]. 4 outputs/thread.
__global__ void __launch_bounds__(256) k_in(const float* __restrict__ x,
                                            const float* __restrict__ in_w,
                                            const float* __restrict__ in_b,
                                            float* __restrict__ h) {
  long tid = (long)blockIdx.x * 256 + threadIdx.x;   // [0, 8*65536*16)
  int o0 = (int)(tid & 15) << 2;
  long p = tid >> 4;                                  // pixel index
  long b = p >> 16; long xy = p & 65535;
  float x0 = x[b * 131072 + xy];
  float x1 = x[b * 131072 + 65536 + xy];
  float4 r;
  r.x = in_b[o0]     + in_w[o0 * 2]     * x0 + in_w[o0 * 2 + 1] * x1;
  r.y = in_b[o0 + 1] + in_w[o0 * 2 + 2] * x0 + in_w[o0 * 2 + 3] * x1;
  r.z = in_b[o0 + 2] + in_w[o0 * 2 + 4] * x0 + in_w[o0 * 2 + 5] * x1;
  r.w = in_b[o0 + 3] + in_w[o0 * 2 + 6] * x0 + in_w[o0 * 2 + 7] * x1;
  *(float4*)(h + (p << 6) + o0) = r;
}

// F1: partial DFT along y. block = (b,x) [2048], thread: cg=t&15 (c0=4*cg), ky=t>>4
__global__ void __launch_bounds__(256) k_f1(const float* __restrict__ h,
                                            const float* __restrict__ costab,
                                            float* __restrict__ Y) {
  __shared__ float T[256];
  int t = threadIdx.x;
  T[t] = costab[t];
  __syncthreads();
  int cg = t & 15, ky = t >> 4;
  int c0 = cg << 2;
  const float* hrow = h + ((long)blockIdx.x << 14) + c0;
  float r0 = 0, r1 = 0, r2 = 0, r3 = 0, i0 = 0, i1 = 0, i2 = 0, i3 = 0;
  int m = 0;
  for (int y = 0; y < 256; ++y) {
    float4 v = *(const float4*)(hrow + (y << 6));
    float cv = T[m], sv = T[(m + 192) & 255];
    r0 += v.x * cv; i0 -= v.x * sv;
    r1 += v.y * cv; i1 -= v.y * sv;
    r2 += v.z * cv; i2 -= v.z * sv;
    r3 += v.w * cv; i3 -= v.w * sv;
    m = (m + ky) & 255;
  }
  const float s = 0.0625f;
  float* out = Y + ((long)blockIdx.x * 16 + ky) * 128 + c0 * 2;
  *(float4*)out = make_float4(r0 * s, i0 * s, r1 * s, i1 * s);
  *(float4*)(out + 4) = make_float4(r2 * s, i2 * s, r3 * s, i3 * s);
}

// F2: partial DFT along x. block = b*16+ky [128], thread: c=t&63, kxg=t>>6 (4 kx each)
__global__ void __launch_bounds__(256) k_f2(const float* __restrict__ Y,
                                            const float* __restrict__ costab,
                                            float* __restrict__ Xf) {
  __shared__ float T[256];
  int t = threadIdx.x;
  T[t] = costab[t];
  __syncthreads();
  int b = blockIdx.x >> 4, ky = blockIdx.x & 15;
  int c = t & 63, kxg = t >> 6;
  float accr[4] = {0, 0, 0, 0}, acci[4] = {0, 0, 0, 0};
  const float* ybase = Y + ((long)b * 4096 + ky) * 128 + c * 2;
  int mj[4];
  #pragma unroll
  for (int j = 0; j < 4; ++j) mj[j] = 0;
  for (int x = 0; x < 256; ++x) {
    float2 v = *(const float2*)(ybase + (long)x * 2048);
    #pragma unroll
    for (int j = 0; j < 4; ++j) {
      int kx = kxg * 4 + j;
      float cv = T[mj[j]], sv = T[(mj[j] + 192) & 255];
      accr[j] += v.x * cv + v.y * sv;   // (yr+i yi)(c - i s)
      acci[j] += v.y * cv - v.x * sv;
      mj[j] = (mj[j] + kx) & 255;
    }
  }
  const float s = 0.0625f;
  #pragma unroll
  for (int j = 0; j < 4; ++j) {
    int kx = kxg * 4 + j;
    float* o = Xf + ((long)b * 64 + c) * 512 + (kx * 16 + ky) * 2;
    o[0] = accr[j] * s;
    o[1] = acci[j] * s;
  }
}

// mode GEMM + I1. block = b*64+o [512]. phase1: thread=mode m; phase2: thread=x.
__global__ void __launch_bounds__(256) k_spec(const float* __restrict__ Xf,
                                              const float* __restrict__ wr,
                                              const float* __restrict__ wi,
                                              const float* __restrict__ costab,
                                              float* __restrict__ A) {
  __shared__ float T[256];
  __shared__ float Gr[256], Gi[256];
  int t = threadIdx.x;
  T[t] = costab[t];
  int b = blockIdx.x >> 6, o = blockIdx.x & 63;
  {
    int m = t;
    float gr = 0, gi = 0;
    const float* xb = Xf + (long)b * 32768 + m * 2;
    const float* wrb = wr + (long)o * 256 + m;    // [i][o][m]
    const float* wib = wi + (long)o * 256 + m;
    for (int i = 0; i < 64; ++i) {
      float xr = xb[(long)i * 512], xi = xb[(long)i * 512 + 1];
      float wrv = wrb[(long)i * 16384], wiv = wib[(long)i * 16384];
      gr += xr * wrv - xi * wiv;
      gi += xr * wiv + xi * wrv;
    }
    Gr[m] = gr; Gi[m] = gi;
  }
  __syncthreads();
  int x = t;
  float ar[16], ai[16];
  #pragma unroll
  for (int ky = 0; ky < 16; ++ky) { ar[ky] = 0.0f; ai[ky] = 0.0f; }
  for (int kx = 0; kx < 16; ++kx) {
    int mm = (kx * x) & 255;
    float cv = T[mm], sv = T[(mm + 192) & 255];
    #pragma unroll
    for (int ky = 0; ky < 16; ++ky) {
      float gr = Gr[kx * 16 + ky], gi = Gi[kx * 16 + ky];
      ar[ky] += gr * cv - gi * sv;     // (gr+i gi)(c + i s)
      ai[ky] += gr * sv + gi * cv;
    }
  }
  const float s = 0.0625f;
  float* ab = A + ((long)b * 256 + x) * 2048 + o * 2;
  #pragma unroll
  for (int ky = 0; ky < 16; ++ky) {
    ab[ky * 128] = ar[ky] * s;
    ab[ky * 128 + 1] = ai[ky] * s;
  }
}

// I2 + pointwise conv + GELU, in place on h.
// v5 (R4 post-mortem): R4's GEMM read h as per-lane float4 at 256B lane
// stride -> every dwordx4 touched 64 cache lines (TA serialization), and
// VGPR=124 gave only ~2 blocks/CU to hide it. Now: stage the 16KB h tile
// (64y x 64c) into LDS with COALESCED float2 loads, GEMM reads LDS rows
// (pad 66 -> ds_read_b64, worst 4-way conflict = 1.58x, cheap). (512,8)
// caps VGPR at 64 (live ~40, fits) -> 8 waves/SIMD, 4 blocks/CU.
__global__ void __launch_bounds__(512, 8) k_pw(float* __restrict__ h,
                                               const float* __restrict__ A,
                                               const float* __restrict__ pwT,
                                               const float* __restrict__ pw_b,
                                               const float* __restrict__ costab) {
  __shared__ float T[256];
  __shared__ float S[64 * 66];
  int t = threadIdx.x;
  if (t < 256) T[t] = costab[t];
  long row = blockIdx.x >> 2;                 // (b,x) in [0,2048)
  int yq = blockIdx.x & 3;
  const float* hbase = h + (row << 14) + ((long)yq << 12);   // 64y x 64c tile
  #pragma unroll
  for (int k = 0; k < 4; ++k) {
    int idx2 = t + (k << 9);                  // [0,2048) float2 elems
    float2 v = *(const float2*)(hbase + idx2 * 2);
    int yy = idx2 >> 5, c2 = idx2 & 31;
    *(float2*)(&S[yy * 66 + c2 * 2]) = v;
  }
  __syncthreads();    // T + S staged; all global h reads for this block done
  int lane = t & 63;
  int oc = __builtin_amdgcn_readfirstlane(t >> 6);   // wave id 0..7
  int o0 = oc << 3;
  int y = (yq << 6) + lane;
  const float* Ab = A + row * 2048;           // [ky][o][2], uniform -> s_load
  float acc[8];
  #pragma unroll
  for (int j = 0; j < 8; ++j) acc[j] = Ab[(o0 + j) * 2];  // ky=0: Re only
  for (int ky = 1; ky < 16; ++ky) {
    int mm = (ky * y) & 255;
    float cv = 2.0f * T[mm], sv = 2.0f * T[(mm + 192) & 255];
    const float* Ak = Ab + (ky << 7) + (o0 << 1);
    #pragma unroll
    for (int j = 0; j < 8; ++j) acc[j] += Ak[j * 2] * cv - Ak[j * 2 + 1] * sv;
  }
  #pragma unroll
  for (int j = 0; j < 8; ++j) acc[j] = acc[j] * 0.0625f + pw_b[o0 + j];
  const float* srow = &S[lane * 66];
  const float* wb = pwT + o0;                 // uniform -> s_load
  #pragma unroll
  for (int c = 0; c < 32; ++c) {
    float2 hv = *(const float2*)(srow + c * 2);
    const float* w0 = wb + ((c * 2) << 6);
    const float* w1 = wb + ((c * 2 + 1) << 6);
    #pragma unroll
    for (int j = 0; j < 8; ++j) acc[j] += hv.x * w0[j] + hv.y * w1[j];
  }
  #pragma unroll
  for (int j = 0; j < 8; ++j) {
    float v = acc[j];
    acc[j] = 0.5f * v * (1.0f + erff(v * 0.70710678118654752f));
  }
  float* orow = h + (row << 14) + ((long)y << 6) + o0;
  *(float4*)(orow)     = make_float4(acc[0], acc[1], acc[2], acc[3]);
  *(float4*)(orow + 4) = make_float4(acc[4], acc[5], acc[6], acc[7]);
}

// output: gelu(o1) then o2. thread = pixel. h streamed (no hv[64] preload).
__global__ void __launch_bounds__(256) k_out(const float* __restrict__ h,
                                             const float* __restrict__ o1T,
                                             const float* __restrict__ o1_b,
                                             const float* __restrict__ o2_w,
                                             const float* __restrict__ o2_b,
                                             float* __restrict__ out) {
  long p = (long)blockIdx.x * 256 + threadIdx.x;
  const float* hp = h + (p << 6);
  float t32[32];
  #pragma unroll
  for (int o = 0; o < 32; ++o) t32[o] = o1_b[o];
  #pragma unroll
  for (int j = 0; j < 16; ++j) {
    float4 hv = *(const float4*)(hp + j * 4);
    #pragma unroll
    for (int k = 0; k < 4; ++k) {
      float hvv = (k == 0) ? hv.x : (k == 1) ? hv.y : (k == 2) ? hv.z : hv.w;
      const float* w = o1T + ((j * 4 + k) << 5);
      #pragma unroll
      for (int o = 0; o < 32; ++o) t32[o] += hvv * w[o];
    }
  }
  float r = o2_b[0];
  #pragma unroll
  for (int o = 0; o < 32; ++o) {
    float v = t32[o];
    v = 0.5f * v * (1.0f + erff(v * 0.70710678118654752f));
    r += o2_w[o] * v;
  }
  out[p] = r;
}

extern "C" void kernel_launch(void* const* d_in, const int* in_sizes, int n_in,
                              void* d_out, int out_size, void* d_ws, size_t ws_size,
                              hipStream_t stream) {
  const float* x       = (const float*)d_in[0];
  const float* in_w    = (const float*)d_in[1];
  const float* in_b    = (const float*)d_in[2];
  const float* spec_wr = (const float*)d_in[3];
  const float* spec_wi = (const float*)d_in[4];
  const float* pw_w    = (const float*)d_in[5];
  const float* pw_b    = (const float*)d_in[6];
  const float* o1_w    = (const float*)d_in[7];
  const float* o1_b    = (const float*)d_in[8];
  const float* o2_w    = (const float*)d_in[9];
  const float* o2_b    = (const float*)d_in[10];
  float* ws = (float*)d_ws;
  float* h      = ws + OFF_H;
  float* YA     = ws + OFF_YA;
  float* Xf     = ws + OFF_XF;
  float* costab = ws + OFF_TAB;
  float* pwT    = ws + OFF_PWT;
  float* o1T    = ws + OFF_O1T;
  float* out = (float*)d_out;

  k_init<<<73, 256, 0, stream>>>(ws, pw_w, o1_w);
  k_in<<<32768, 256, 0, stream>>>(x, in_w, in_b, h);
  for (int l = 0; l < NLAYER; ++l) {
    k_f1<<<2048, 256, 0, stream>>>(h, costab, YA);
    k_f2<<<128, 256, 0, stream>>>(YA, costab, Xf);
    k_spec<<<512, 256, 0, stream>>>(Xf, spec_wr + (long)l * 1048576,
                                    spec_wi + (long)l * 1048576, costab, YA);
    k_pw<<<8192, 512, 0, stream>>>(h, YA, pwT + l * 4096, pw_b + l * 64, costab);
  }
  k_out<<<2048, 256, 0, stream>>>(h, o1T, o1_b, o2_w, o2_b, out);
}

// Round 6
// 4206.918 us; speedup vs baseline: 3.4196x; 3.4196x over previous
//
#include <hip/hip_runtime.h>
#include <math.h>

// FNO2d: B=8, CIN=2, COUT=1, W0=64, modes 16x16, NL=4, H=W=256
// h stored channels-last: [B][H][W][64]
// Y (F1 out): [B][H(x)][16ky][64c][2]   (shares buffer with A)
// Xf (F2 out): [B][64c][256m][2], m = kx*16+ky
// A (I1 out): [B][H(x)][16ky][64o][2]
//
// HARD-WON RULE (R2/R3/R5): NEVER use the min-waves arg of __launch_bounds__
// on kernels with per-thread accumulator arrays -- the backend spills to meet
// the occupancy target (VGPR tier 64/32) and FETCH/WRITE balloon to GBs.

#define NLAYER 4

// ws offsets in floats
#define OFF_H    0L
#define SZ_H     33554432L            // 8*256*256*64
#define OFF_YA   33554432L
#define SZ_YA    4194304L             // 8*256*16*64*2
#define OFF_XF   37748736L
#define SZ_XF    262144L              // 8*64*256*2
#define OFF_TAB  38010880L
#define OFF_PWT  38011136L            // 4*64*64
#define OFF_O1T  38027520L            // 64*32
#define WS_FLOATS 38029568L

__global__ void k_init(float* __restrict__ ws, const float* __restrict__ pw_w,
                       const float* __restrict__ o1_w) {
  float* costab = ws + OFF_TAB;
  float* pwT = ws + OFF_PWT;
  float* o1T = ws + OFF_O1T;
  int t = blockIdx.x * blockDim.x + threadIdx.x;
  int stride = gridDim.x * blockDim.x;
  for (int m = t; m < 256; m += stride)
    costab[m] = (float)cos((double)m * (3.14159265358979323846 / 128.0));
  for (int idx = t; idx < NLAYER * 64 * 64; idx += stride) {
    int l = idx >> 12; int r = idx & 4095; int i = r >> 6; int o = r & 63;
    pwT[idx] = pw_w[((l * 64 + o) << 6) + i];   // pwT[l][i][o] = pw_w[l][o][i]
  }
  for (int idx = t; idx < 64 * 32; idx += stride) {
    int i = idx >> 5; int o = idx & 31;
    o1T[idx] = o1_w[(o << 6) + i];              // o1T[i][o] = o1_w[o][i]
  }
}

// input 1x1 conv: x [B][2][H][W] -> h [B][H][W][64]. 4 outputs/thread.
__global__ void __launch_bounds__(256) k_in(const float* __restrict__ x,
                                            const float* __restrict__ in_w,
                                            const float* __restrict__ in_b,
                                            float* __restrict__ h) {
  long tid = (long)blockIdx.x * 256 + threadIdx.x;   // [0, 8*65536*16)
  int o0 = (int)(tid & 15) << 2;
  long p = tid >> 4;                                  // pixel index
  long b = p >> 16; long xy = p & 65535;
  float x0 = x[b * 131072 + xy];
  float x1 = x[b * 131072 + 65536 + xy];
  float4 r;
  r.x = in_b[o0]     + in_w[o0 * 2]     * x0 + in_w[o0 * 2 + 1] * x1;
  r.y = in_b[o0 + 1] + in_w[o0 * 2 + 2] * x0 + in_w[o0 * 2 + 3] * x1;
  r.z = in_b[o0 + 2] + in_w[o0 * 2 + 4] * x0 + in_w[o0 * 2 + 5] * x1;
  r.w = in_b[o0 + 3] + in_w[o0 * 2 + 6] * x0 + in_w[o0 * 2 + 7] * x1;
  *(float4*)(h + (p << 6) + o0) = r;
}

// F1: partial DFT along y. block = (b,x) [2048], thread: cg=t&15 (c0=4*cg), ky=t>>4
__global__ void __launch_bounds__(256) k_f1(const float* __restrict__ h,
                                            const float* __restrict__ costab,
                                            float* __restrict__ Y) {
  __shared__ float T[256];
  int t = threadIdx.x;
  T[t] = costab[t];
  __syncthreads();
  int cg = t & 15, ky = t >> 4;
  int c0 = cg << 2;
  const float* hrow = h + ((long)blockIdx.x << 14) + c0;
  float r0 = 0, r1 = 0, r2 = 0, r3 = 0, i0 = 0, i1 = 0, i2 = 0, i3 = 0;
  int m = 0;
  for (int y = 0; y < 256; ++y) {
    float4 v = *(const float4*)(hrow + (y << 6));
    float cv = T[m], sv = T[(m + 192) & 255];
    r0 += v.x * cv; i0 -= v.x * sv;
    r1 += v.y * cv; i1 -= v.y * sv;
    r2 += v.z * cv; i2 -= v.z * sv;
    r3 += v.w * cv; i3 -= v.w * sv;
    m = (m + ky) & 255;
  }
  const float s = 0.0625f;
  float* out = Y + ((long)blockIdx.x * 16 + ky) * 128 + c0 * 2;
  *(float4*)out = make_float4(r0 * s, i0 * s, r1 * s, i1 * s);
  *(float4*)(out + 4) = make_float4(r2 * s, i2 * s, r3 * s, i3 * s);
}

// F2: partial DFT along x. block = b*16+ky [128], thread: c=t&63, kxg=t>>6 (4 kx each)
__global__ void __launch_bounds__(256) k_f2(const float* __restrict__ Y,
                                            const float* __restrict__ costab,
                                            float* __restrict__ Xf) {
  __shared__ float T[256];
  int t = threadIdx.x;
  T[t] = costab[t];
  __syncthreads();
  int b = blockIdx.x >> 4, ky = blockIdx.x & 15;
  int c = t & 63, kxg = t >> 6;
  float accr[4] = {0, 0, 0, 0}, acci[4] = {0, 0, 0, 0};
  const float* ybase = Y + ((long)b * 4096 + ky) * 128 + c * 2;
  int mj[4];
  #pragma unroll
  for (int j = 0; j < 4; ++j) mj[j] = 0;
  for (int x = 0; x < 256; ++x) {
    float2 v = *(const float2*)(ybase + (long)x * 2048);
    #pragma unroll
    for (int j = 0; j < 4; ++j) {
      int kx = kxg * 4 + j;
      float cv = T[mj[j]], sv = T[(mj[j] + 192) & 255];
      accr[j] += v.x * cv + v.y * sv;   // (yr+i yi)(c - i s)
      acci[j] += v.y * cv - v.x * sv;
      mj[j] = (mj[j] + kx) & 255;
    }
  }
  const float s = 0.0625f;
  #pragma unroll
  for (int j = 0; j < 4; ++j) {
    int kx = kxg * 4 + j;
    float* o = Xf + ((long)b * 64 + c) * 512 + (kx * 16 + ky) * 2;
    o[0] = accr[j] * s;
    o[1] = acci[j] * s;
  }
}

// mode GEMM + I1. block = b*64+o [512]. phase1: thread=mode m; phase2: thread=x.
__global__ void __launch_bounds__(256) k_spec(const float* __restrict__ Xf,
                                              const float* __restrict__ wr,
                                              const float* __restrict__ wi,
                                              const float* __restrict__ costab,
                                              float* __restrict__ A) {
  __shared__ float T[256];
  __shared__ float Gr[256], Gi[256];
  int t = threadIdx.x;
  T[t] = costab[t];
  int b = blockIdx.x >> 6, o = blockIdx.x & 63;
  {
    int m = t;
    float gr = 0, gi = 0;
    const float* xb = Xf + (long)b * 32768 + m * 2;
    const float* wrb = wr + (long)o * 256 + m;    // [i][o][m]
    const float* wib = wi + (long)o * 256 + m;
    for (int i = 0; i < 64; ++i) {
      float xr = xb[(long)i * 512], xi = xb[(long)i * 512 + 1];
      float wrv = wrb[(long)i * 16384], wiv = wib[(long)i * 16384];
      gr += xr * wrv - xi * wiv;
      gi += xr * wiv + xi * wrv;
    }
    Gr[m] = gr; Gi[m] = gi;
  }
  __syncthreads();
  int x = t;
  float ar[16], ai[16];
  #pragma unroll
  for (int ky = 0; ky < 16; ++ky) { ar[ky] = 0.0f; ai[ky] = 0.0f; }
  for (int kx = 0; kx < 16; ++kx) {
    int mm = (kx * x) & 255;
    float cv = T[mm], sv = T[(mm + 192) & 255];
    #pragma unroll
    for (int ky = 0; ky < 16; ++ky) {
      float gr = Gr[kx * 16 + ky], gi = Gi[kx * 16 + ky];
      ar[ky] += gr * cv - gi * sv;     // (gr+i gi)(c + i s)
      ai[ky] += gr * sv + gi * cv;
    }
  }
  const float s = 0.0625f;
  float* ab = A + ((long)b * 256 + x) * 2048 + o * 2;
  #pragma unroll
  for (int ky = 0; ky < 16; ++ky) {
    ab[ky * 128] = ar[ky] * s;
    ab[ky * 128 + 1] = ai[ky] * s;
  }
}

// I2 + pointwise conv + GELU, in place on h.
// v6 = v5 structure (LDS-staged h tile, coalesced float2 staging, ds_read_b64
// GEMM feeds, s_load weights) but with PLAIN __launch_bounds__(512).
// R5's (512,8) forced a 32-VGPR allocation -> 10 GB of spill traffic.
__global__ void __launch_bounds__(512) k_pw(float* __restrict__ h,
                                            const float* __restrict__ A,
                                            const float* __restrict__ pwT,
                                            const float* __restrict__ pw_b,
                                            const float* __restrict__ costab) {
  __shared__ float T[256];
  __shared__ float S[64 * 66];
  int t = threadIdx.x;
  if (t < 256) T[t] = costab[t];
  long row = blockIdx.x >> 2;                 // (b,x) in [0,2048)
  int yq = blockIdx.x & 3;
  const float* hbase = h + (row << 14) + ((long)yq << 12);   // 64y x 64c tile
  #pragma unroll
  for (int k = 0; k < 4; ++k) {
    int idx2 = t + (k << 9);                  // [0,2048) float2 elems
    float2 v = *(const float2*)(hbase + idx2 * 2);
    int yy = idx2 >> 5, c2 = idx2 & 31;
    *(float2*)(&S[yy * 66 + c2 * 2]) = v;
  }
  __syncthreads();    // T + S staged; all global h reads for this block done
  int lane = t & 63;
  int oc = __builtin_amdgcn_readfirstlane(t >> 6);   // wave id 0..7
  int o0 = oc << 3;
  int y = (yq << 6) + lane;
  const float* Ab = A + row * 2048;           // [ky][o][2], uniform -> s_load
  float acc[8];
  #pragma unroll
  for (int j = 0; j < 8; ++j) acc[j] = Ab[(o0 + j) * 2];  // ky=0: Re only
  for (int ky = 1; ky < 16; ++ky) {
    int mm = (ky * y) & 255;
    float cv = 2.0f * T[mm], sv = 2.0f * T[(mm + 192) & 255];
    const float* Ak = Ab + (ky << 7) + (o0 << 1);
    #pragma unroll
    for (int j = 0; j < 8; ++j) acc[j] += Ak[j * 2] * cv - Ak[j * 2 + 1] * sv;
  }
  #pragma unroll
  for (int j = 0; j < 8; ++j) acc[j] = acc[j] * 0.0625f + pw_b[o0 + j];
  const float* srow = &S[lane * 66];
  const float* wb = pwT + o0;                 // uniform -> s_load
  #pragma unroll
  for (int c = 0; c < 32; ++c) {
    float2 hv = *(const float2*)(srow + c * 2);
    const float* w0 = wb + ((c * 2) << 6);
    const float* w1 = wb + ((c * 2 + 1) << 6);
    #pragma unroll
    for (int j = 0; j < 8; ++j) acc[j] += hv.x * w0[j] + hv.y * w1[j];
  }
  #pragma unroll
  for (int j = 0; j < 8; ++j) {
    float v = acc[j];
    acc[j] = 0.5f * v * (1.0f + erff(v * 0.70710678118654752f));
  }
  float* orow = h + (row << 14) + ((long)y << 6) + o0;
  *(float4*)(orow)     = make_float4(acc[0], acc[1], acc[2], acc[3]);
  *(float4*)(orow + 4) = make_float4(acc[4], acc[5], acc[6], acc[7]);
}

// output: gelu(o1) then o2. thread = pixel. h streamed (no hv[64] preload).
__global__ void __launch_bounds__(256) k_out(const float* __restrict__ h,
                                             const float* __restrict__ o1T,
                                             const float* __restrict__ o1_b,
                                             const float* __restrict__ o2_w,
                                             const float* __restrict__ o2_b,
                                             float* __restrict__ out) {
  long p = (long)blockIdx.x * 256 + threadIdx.x;
  const float* hp = h + (p << 6);
  float t32[32];
  #pragma unroll
  for (int o = 0; o < 32; ++o) t32[o] = o1_b[o];
  #pragma unroll
  for (int j = 0; j < 16; ++j) {
    float4 hv = *(const float4*)(hp + j * 4);
    #pragma unroll
    for (int k = 0; k < 4; ++k) {
      float hvv = (k == 0) ? hv.x : (k == 1) ? hv.y : (k == 2) ? hv.z : hv.w;
      const float* w = o1T + ((j * 4 + k) << 5);
      #pragma unroll
      for (int o = 0; o < 32; ++o) t32[o] += hvv * w[o];
    }
  }
  float r = o2_b[0];
  #pragma unroll
  for (int o = 0; o < 32; ++o) {
    float v = t32[o];
    v = 0.5f * v * (1.0f + erff(v * 0.70710678118654752f));
    r += o2_w[o] * v;
  }
  out[p] = r;
}

extern "C" void kernel_launch(void* const* d_in, const int* in_sizes, int n_in,
                              void* d_out, int out_size, void* d_ws, size_t ws_size,
                              hipStream_t stream) {
  const float* x       = (const float*)d_in[0];
  const float* in_w    = (const float*)d_in[1];
  const float* in_b    = (const float*)d_in[2];
  const float* spec_wr = (const float*)d_in[3];
  const float* spec_wi = (const float*)d_in[4];
  const float* pw_w    = (const float*)d_in[5];
  const float* pw_b    = (const float*)d_in[6];
  const float* o1_w    = (const float*)d_in[7];
  const float* o1_b    = (const float*)d_in[8];
  const float* o2_w    = (const float*)d_in[9];
  const float* o2_b    = (const float*)d_in[10];
  float* ws = (float*)d_ws;
  float* h      = ws + OFF_H;
  float* YA     = ws + OFF_YA;
  float* Xf     = ws + OFF_XF;
  float* costab = ws + OFF_TAB;
  float* pwT    = ws + OFF_PWT;
  float* o1T    = ws + OFF_O1T;
  float* out = (float*)d_out;

  k_init<<<73, 256, 0, stream>>>(ws, pw_w, o1_w);
  k_in<<<32768, 256, 0, stream>>>(x, in_w, in_b, h);
  for (int l = 0; l < NLAYER; ++l) {
    k_f1<<<2048, 256, 0, stream>>>(h, costab, YA);
    k_f2<<<128, 256, 0, stream>>>(YA, costab, Xf);
    k_spec<<<512, 256, 0, stream>>>(Xf, spec_wr + (long)l * 1048576,
                                    spec_wi + (long)l * 1048576, costab, YA);
    k_pw<<<8192, 512, 0, stream>>>(h, YA, pwT + l * 4096, pw_b + l * 64, costab);
  }
  k_out<<<2048, 256, 0, stream>>>(h, o1T, o1_b, o2_w, o2_b, out);
}